// Round 7
// baseline (84.176 us; speedup 1.0000x reference)
//
#include <hip/hip_runtime.h>

#define D_DIM 1024
#define H_DIM 64
#define T_SEQ 2048
#define B_SZ  8
#define M_TOT (B_SZ * T_SEQ)

typedef __attribute__((ext_vector_type(4))) float f32x4;
typedef __attribute__((ext_vector_type(8))) short s16x8;
typedef __attribute__((ext_vector_type(8))) unsigned short u16x8;
typedef __attribute__((ext_vector_type(4))) unsigned short u16x4;

__device__ __forceinline__ unsigned short f2bf(float x) {
    union { float f; unsigned u; } v; v.f = x;
    unsigned r = (v.u + 0x7FFFu + ((v.u >> 16) & 1u)) >> 16;   // RNE
    return (unsigned short)r;
}
__device__ __forceinline__ float bf2f(unsigned short u) {
    union { unsigned u; float f; } v; v.u = ((unsigned)u) << 16; return v.f;
}

__device__ __forceinline__ f32x4 mfma_bf16(u16x8 a, u16x8 b, f32x4 c) {
    return __builtin_amdgcn_mfma_f32_16x16x32_bf16(
        __builtin_bit_cast(s16x8, a), __builtin_bit_cast(s16x8, b), c, 0, 0, 0);
}

// ---------------------------------------------------------------------------
// Kernel 0: W [1024][64] fp32 (x3) -> Wt bf16 [192][1024]  (Wt[c][k] = W[k][c])
// ---------------------------------------------------------------------------
__global__ __launch_bounds__(256) void wtrans_kernel(
    const float* __restrict__ Wq, const float* __restrict__ Wk,
    const float* __restrict__ Wv, unsigned short* __restrict__ Wt)
{
    __shared__ unsigned short tw[64 * 72];
    const int mat = blockIdx.x / 16;
    const int k0  = (blockIdx.x % 16) * 64;
    const float* W = (mat == 0) ? Wq : (mat == 1) ? Wk : Wv;
    const int tid = threadIdx.x;

    {
        const int r = tid >> 2, c0 = (tid & 3) * 16;
        #pragma unroll
        for (int jj = 0; jj < 4; ++jj) {
            float4 v = *reinterpret_cast<const float4*>(&W[(size_t)(k0 + r) * H_DIM + c0 + jj * 4]);
            u16x4 u = { f2bf(v.x), f2bf(v.y), f2bf(v.z), f2bf(v.w) };
            *reinterpret_cast<u16x4*>(&tw[r * 72 + c0 + jj * 4]) = u;
        }
    }
    __syncthreads();
    {
        const int c = tid >> 2, kc = (tid & 3) * 16;
        unsigned short tmp[16];
        #pragma unroll
        for (int kk = 0; kk < 16; ++kk) tmp[kk] = tw[(kc + kk) * 72 + c];
        #pragma unroll
        for (int h = 0; h < 2; ++h)
            *reinterpret_cast<u16x8*>(&Wt[((size_t)mat * 64 + c) * D_DIM + k0 + kc + h * 8]) =
                *reinterpret_cast<u16x8*>(&tmp[h * 8]);
    }
}

// ---------------------------------------------------------------------------
// Kernel 1: QKV projection v4.  M=16 tiles, grid 1024, BK=64.
// KEY CHANGE: W B-fragments load DIRECTLY from global (L2-resident Wt) into
// registers with 1-step prefetch — no W LDS staging (was ~950 MB LDS traffic,
// the round-5 bottleneck). Only x (4 KB/step) goes through LDS.
// ---------------------------------------------------------------------------
__global__ __launch_bounds__(256) void qkv_proj_kernel(
    const float* __restrict__ x, const unsigned short* __restrict__ Wt,
    unsigned short* __restrict__ Qg, unsigned short* __restrict__ Kg,
    unsigned short* __restrict__ Vtg)
{
    __shared__ unsigned short xs[16 * 72];    // [16][64+pad] bf16
    __shared__ unsigned short vt[64 * 24];    // [h][16t+pad]

    const int tid = threadIdx.x;
    const int w = tid >> 6, l = tid & 63, g = l >> 4, n = l & 15;
    const int m0 = blockIdx.x * 16;

    f32x4 acc0 = {0.f,0.f,0.f,0.f}, acc1 = {0.f,0.f,0.f,0.f}, acc2 = {0.f,0.f,0.f,0.f};

    // per-lane W fragment pointers: B-frag(ct) lane(g,n) = Wt[w*48+ct*16+n][k + g*8]
    const unsigned short* wp0 = &Wt[(size_t)(w * 48 +  0 + n) * D_DIM + g * 8];
    const unsigned short* wp1 = &Wt[(size_t)(w * 48 + 16 + n) * D_DIM + g * 8];
    const unsigned short* wp2 = &Wt[(size_t)(w * 48 + 32 + n) * D_DIM + g * 8];

    // x staging: 16 rows x 64 cols fp32, 1 float4/thread
    const int sr = tid >> 4, sc = (tid & 15) * 4;
    float4 xr = *reinterpret_cast<const float4*>(&x[(size_t)(m0 + sr) * D_DIM + sc]);

    // W prefetch (named regs, all compile-time indexed)
    u16x8 c00 = *reinterpret_cast<const u16x8*>(wp0);
    u16x8 c10 = *reinterpret_cast<const u16x8*>(wp1);
    u16x8 c20 = *reinterpret_cast<const u16x8*>(wp2);
    u16x8 c01 = *reinterpret_cast<const u16x8*>(wp0 + 32);
    u16x8 c11 = *reinterpret_cast<const u16x8*>(wp1 + 32);
    u16x8 c21 = *reinterpret_cast<const u16x8*>(wp2 + 32);

    for (int ks = 0; ks < 16; ++ks) {
        __syncthreads();
        {
            u16x4 xv = { f2bf(xr.x), f2bf(xr.y), f2bf(xr.z), f2bf(xr.w) };
            *reinterpret_cast<u16x4*>(&xs[sr * 72 + sc]) = xv;
        }
        __syncthreads();

        // stash current W frags; prefetch next K-step
        u16x8 u00 = c00, u10 = c10, u20 = c20, u01 = c01, u11 = c11, u21 = c21;
        if (ks < 15) {
            const int k0 = (ks + 1) * 64;
            xr = *reinterpret_cast<const float4*>(&x[(size_t)(m0 + sr) * D_DIM + k0 + sc]);
            c00 = *reinterpret_cast<const u16x8*>(wp0 + k0);
            c10 = *reinterpret_cast<const u16x8*>(wp1 + k0);
            c20 = *reinterpret_cast<const u16x8*>(wp2 + k0);
            c01 = *reinterpret_cast<const u16x8*>(wp0 + k0 + 32);
            c11 = *reinterpret_cast<const u16x8*>(wp1 + k0 + 32);
            c21 = *reinterpret_cast<const u16x8*>(wp2 + k0 + 32);
        }

        const u16x8 af0 = *reinterpret_cast<const u16x8*>(&xs[n * 72 + g * 8]);
        const u16x8 af1 = *reinterpret_cast<const u16x8*>(&xs[n * 72 + 32 + g * 8]);
        acc0 = mfma_bf16(af0, u00, acc0);
        acc1 = mfma_bf16(af0, u10, acc1);
        acc2 = mfma_bf16(af0, u20, acc2);
        acc0 = mfma_bf16(af1, u01, acc0);
        acc1 = mfma_bf16(af1, u11, acc1);
        acc2 = mfma_bf16(af1, u21, acc2);
    }

    // epilogue: D layout col = lane&15, row = (lane>>4)*4 + reg
    const int b = m0 >> 11, t0 = m0 & (T_SEQ - 1);
    const f32x4 accs[3] = { acc0, acc1, acc2 };
    #pragma unroll
    for (int ct = 0; ct < 3; ++ct) {
        const int c = w * 48 + ct * 16 + n;
        #pragma unroll
        for (int r = 0; r < 4; ++r) {
            const int rin = g * 4 + r;
            const float val = accs[ct][r];
            if (c < 64)
                Qg[(size_t)(m0 + rin) * H_DIM + c] = f2bf(val * 0.125f);
            else if (c < 128)
                Kg[(size_t)(m0 + rin) * H_DIM + (c - 64)] = f2bf(val);
            else
                vt[(c - 128) * 24 + rin] = f2bf(val);
        }
    }
    __syncthreads();
    {   // Vt[b][h][t] coalesced: 64h x 16t = 1 u16x4/thread
        const int h = tid >> 2, c4 = (tid & 3) * 4;
        *reinterpret_cast<u16x4*>(&Vtg[((size_t)(b * 64 + h)) * T_SEQ + t0 + c4]) =
            *reinterpret_cast<const u16x4*>(&vt[h * 24 + c4]);
    }
}

// ---------------------------------------------------------------------------
// Kernel 2: causal flash attention (unchanged from round 5 PASS).
// Block = 32 queries x 4 waves: wave = (qg, kh); 128-key LDS tiles.
// ---------------------------------------------------------------------------
__global__ __launch_bounds__(256) void attn_kernel(
    const unsigned short* __restrict__ Qg, const unsigned short* __restrict__ Kg,
    const unsigned short* __restrict__ Vtg, float* __restrict__ out)
{
    __shared__ unsigned short Kl[128 * 72];   // [key][h]
    __shared__ unsigned short Vl[64 * 136];   // [h][key]
    __shared__ float Om[2][64][20];           // merge buffer
    __shared__ float mred[4][64], lred[4][64];

    const int tid = threadIdx.x;
    const int wv = tid >> 6, qg = wv >> 1, kh = wv & 1;
    const int l = tid & 63, g = l >> 4, n = l & 15;

    const int i = blockIdx.x, hi = i >> 8, rest = i & 255;
    const int b = hi * 4 + (rest >> 6), j = rest & 63;
    const int qt = hi ? (63 - j) : j;
    const int q0 = qt * 32;
    const int qrow = q0 + qg * 16 + n;
    const int qmax = q0 + qg * 16 + 15;
    const int nk = (qt >> 2) + 1;

    const unsigned short* Qb = Qg + (size_t)b * T_SEQ * H_DIM;
    const unsigned short* Kb = Kg + (size_t)b * T_SEQ * H_DIM;
    const unsigned short* Vb = Vtg + (size_t)b * H_DIM * T_SEQ;

    const u16x8 qf0 = *reinterpret_cast<const u16x8*>(&Qb[(size_t)qrow * H_DIM + g * 8]);
    const u16x8 qf1 = *reinterpret_cast<const u16x8*>(&Qb[(size_t)qrow * H_DIM + 32 + g * 8]);

    f32x4 oacc[4];
    #pragma unroll
    for (int hb = 0; hb < 4; ++hb) oacc[hb] = f32x4{0.f, 0.f, 0.f, 0.f};
    float mrun = -1e30f, lrun = 0.f;

    u16x8 kst[4], vst[4];
    #pragma unroll
    for (int ii = 0; ii < 4; ++ii) {
        const int u = tid + ii * 256;
        const int kr = u >> 3, kc = (u & 7) * 8;
        const int vh = u >> 4, vc = (u & 15) * 8;
        kst[ii] = *reinterpret_cast<const u16x8*>(&Kb[(size_t)kr * H_DIM + kc]);
        vst[ii] = *reinterpret_cast<const u16x8*>(&Vb[(size_t)vh * T_SEQ + vc]);
    }

    for (int t = 0; t < nk; ++t) {
        __syncthreads();
        #pragma unroll
        for (int ii = 0; ii < 4; ++ii) {
            const int u = tid + ii * 256;
            const int kr = u >> 3, kc = (u & 7) * 8;
            const int vh = u >> 4, vc = (u & 15) * 8;
            *reinterpret_cast<u16x8*>(&Kl[kr * 72 + kc]) = kst[ii];
            *reinterpret_cast<u16x8*>(&Vl[vh * 136 + vc]) = vst[ii];
        }
        __syncthreads();
        if (t + 1 < nk) {
            const int k0n = (t + 1) * 128;
            #pragma unroll
            for (int ii = 0; ii < 4; ++ii) {
                const int u = tid + ii * 256;
                const int kr = u >> 3, kc = (u & 7) * 8;
                const int vh = u >> 4, vc = (u & 15) * 8;
                kst[ii] = *reinterpret_cast<const u16x8*>(&Kb[(size_t)(k0n + kr) * H_DIM + kc]);
                vst[ii] = *reinterpret_cast<const u16x8*>(&Vb[(size_t)vh * T_SEQ + k0n + vc]);
            }
        }

        const int kbase = kh * 64;
        if (t * 128 + kbase <= qmax) {
            f32x4 s[4];
            #pragma unroll
            for (int kb = 0; kb < 4; ++kb) {
                const u16x8 kf0 = *reinterpret_cast<const u16x8*>(&Kl[(kbase + kb * 16 + n) * 72 + g * 8]);
                const u16x8 kf1 = *reinterpret_cast<const u16x8*>(&Kl[(kbase + kb * 16 + n) * 72 + 32 + g * 8]);
                f32x4 z = f32x4{0.f, 0.f, 0.f, 0.f};
                z = mfma_bf16(kf0, qf0, z);
                z = mfma_bf16(kf1, qf1, z);
                s[kb] = z;
            }

            float sv[16];
            float tmax = -1e30f;
            #pragma unroll
            for (int kb = 0; kb < 4; ++kb)
                #pragma unroll
                for (int r = 0; r < 4; ++r) {
                    const int kk = t * 128 + kbase + kb * 16 + g * 4 + r;
                    float v = s[kb][r];
                    v = (kk <= qrow) ? v : -1e30f;
                    sv[kb * 4 + r] = v;
                    tmax = fmaxf(tmax, v);
                }
            tmax = fmaxf(tmax, __shfl_xor(tmax, 16));
            tmax = fmaxf(tmax, __shfl_xor(tmax, 32));
            const float mnew = fmaxf(mrun, tmax);
            const float scale = __expf(mrun - mnew);
            #pragma unroll
            for (int hb = 0; hb < 4; ++hb) oacc[hb] *= scale;
            lrun = lrun * scale;
            mrun = mnew;

            unsigned short pb[16];
            float ps = 0.f;
            #pragma unroll
            for (int q = 0; q < 16; ++q) {
                const float p = (sv[q] > -1e29f) ? __expf(sv[q] - mnew) : 0.f;
                pb[q] = f2bf(p);
                ps += bf2f(pb[q]);
            }
            ps += __shfl_xor(ps, 16);
            ps += __shfl_xor(ps, 32);
            lrun += ps;

            u16x8 pa0, pa1;
            #pragma unroll
            for (int q = 0; q < 8; ++q) { pa0[q] = pb[q]; pa1[q] = pb[8 + q]; }

            #pragma unroll
            for (int hb = 0; hb < 4; ++hb) {
                const unsigned short* vp = &Vl[(hb * 16 + n) * 136 + kbase + 4 * g];
                const u16x4 a0 = *reinterpret_cast<const u16x4*>(vp);
                const u16x4 a1 = *reinterpret_cast<const u16x4*>(vp + 16);
                const u16x4 b0 = *reinterpret_cast<const u16x4*>(vp + 32);
                const u16x4 b1 = *reinterpret_cast<const u16x4*>(vp + 48);
                const u16x8 vf0 = { a0[0], a0[1], a0[2], a0[3], a1[0], a1[1], a1[2], a1[3] };
                const u16x8 vf1 = { b0[0], b0[1], b0[2], b0[3], b1[0], b1[1], b1[2], b1[3] };
                oacc[hb] = mfma_bf16(vf0, pa0, oacc[hb]);
                oacc[hb] = mfma_bf16(vf1, pa1, oacc[hb]);
            }
        }
    }

    // cross-wave (kh pair) merge
    mred[wv][l] = mrun;
    lred[wv][l] = lrun;
    __syncthreads();
    const float m0v = mred[qg * 2][l],     l0v = lred[qg * 2][l];
    const float m1v = mred[qg * 2 + 1][l], l1v = lred[qg * 2 + 1][l];
    const float M = fmaxf(m0v, m1v);
    const float alpha = __expf(mrun - M);
    const float Lsum = l0v * __expf(m0v - M) + l1v * __expf(m1v - M);
    #pragma unroll
    for (int hb = 0; hb < 4; ++hb) oacc[hb] *= alpha;

    if (kh == 1) {
        #pragma unroll
        for (int hb = 0; hb < 4; ++hb)
            *reinterpret_cast<f32x4*>(&Om[qg][l][hb * 4]) = oacc[hb];
    }
    __syncthreads();
    if (kh == 0) {
        const float inv = 1.0f / Lsum;
        #pragma unroll
        for (int hb = 0; hb < 4; ++hb) {
            const f32x4 o2 = *reinterpret_cast<const f32x4*>(&Om[qg][l][hb * 4]);
            float4 o;
            o.x = (oacc[hb][0] + o2[0]) * inv;
            o.y = (oacc[hb][1] + o2[1]) * inv;
            o.z = (oacc[hb][2] + o2[2]) * inv;
            o.w = (oacc[hb][3] + o2[3]) * inv;
            *reinterpret_cast<float4*>(
                &out[((size_t)b * T_SEQ + qrow) * H_DIM + hb * 16 + 4 * g]) = o;
        }
    }
}

// ---------------------------------------------------------------------------
extern "C" void kernel_launch(void* const* d_in, const int* in_sizes, int n_in,
                              void* d_out, int out_size, void* d_ws, size_t ws_size,
                              hipStream_t stream) {
    const float* x  = (const float*)d_in[0];
    const float* Wq = (const float*)d_in[1];
    const float* Wk = (const float*)d_in[2];
    const float* Wv = (const float*)d_in[3];

    unsigned short* Qg  = (unsigned short*)d_ws;
    unsigned short* Kg  = Qg + (size_t)M_TOT * H_DIM;
    unsigned short* Vtg = Kg + (size_t)M_TOT * H_DIM;
    unsigned short* Wt  = Vtg + (size_t)M_TOT * H_DIM;
    float* o = (float*)d_out;

    wtrans_kernel<<<48, 256, 0, stream>>>(Wq, Wk, Wv, Wt);
    qkv_proj_kernel<<<M_TOT / 16, 256, 0, stream>>>(x, Wt, Qg, Kg, Vtg);
    attn_kernel<<<512, 256, 0, stream>>>(Qg, Kg, Vtg, o);
}

// Round 9
// 58.067 us; speedup vs baseline: 1.4497x; 1.4497x over previous
//
#include <hip/hip_runtime.h>

#define D_DIM 1024
#define H_DIM 64
#define T_SEQ 2048
#define B_SZ  8
#define M_TOT (B_SZ * T_SEQ)

typedef __attribute__((ext_vector_type(4))) float f32x4;
typedef __attribute__((ext_vector_type(8))) short s16x8;
typedef __attribute__((ext_vector_type(8))) unsigned short u16x8;
typedef __attribute__((ext_vector_type(4))) unsigned short u16x4;

__device__ __forceinline__ unsigned short f2bf(float x) {
    union { float f; unsigned u; } v; v.f = x;
    unsigned r = (v.u + 0x7FFFu + ((v.u >> 16) & 1u)) >> 16;   // RNE
    return (unsigned short)r;
}
__device__ __forceinline__ float bf2f(unsigned short u) {
    union { unsigned u; float f; } v; v.u = ((unsigned)u) << 16; return v.f;
}

__device__ __forceinline__ f32x4 mfma_bf16(u16x8 a, u16x8 b, f32x4 c) {
    return __builtin_amdgcn_mfma_f32_16x16x32_bf16(
        __builtin_bit_cast(s16x8, a), __builtin_bit_cast(s16x8, b), c, 0, 0, 0);
}

// ---------------------------------------------------------------------------
// Kernel 0: W fp32 [1024][64] (x3) -> WF bf16 in MFMA B-fragment order.
// WF[fid][lane][slot]: fid = ks*24 + colTile*2 + kh   (colTile = col/16, 0..11)
//   *** ks stride is 24 (= 12 colTiles x 2 kh) — was 12 in round 7: ALIASED ***
// lane = (g<<4)|n holds W[k = ks*64+kh*32+g*8+slot][colTile*16+n].
// Proj reads each fragment as ONE contiguous 1KB wave-load.
// ---------------------------------------------------------------------------
__global__ __launch_bounds__(256) void wtrans_kernel(
    const float* __restrict__ Wq, const float* __restrict__ Wk,
    const float* __restrict__ Wv, unsigned short* __restrict__ WF)
{
    __shared__ unsigned short tw[64 * 72];   // tw[kk][c] = bf16(W[k0+kk][c])
    const int mat = blockIdx.x / 16;
    const int k0  = (blockIdx.x % 16) * 64;
    const int ks  = k0 >> 6;
    const float* W = (mat == 0) ? Wq : (mat == 1) ? Wk : Wv;
    const int tid = threadIdx.x;

    {   // stage 64k x 64c tile, coalesced fp32 reads
        const int r = tid >> 2, c0 = (tid & 3) * 16;
        #pragma unroll
        for (int jj = 0; jj < 4; ++jj) {
            float4 v = *reinterpret_cast<const float4*>(&W[(size_t)(k0 + r) * H_DIM + c0 + jj * 4]);
            u16x4 u = { f2bf(v.x), f2bf(v.y), f2bf(v.z), f2bf(v.w) };
            *reinterpret_cast<u16x4*>(&tw[r * 72 + c0 + jj * 4]) = u;
        }
    }
    __syncthreads();
    // 512 fragment slices of 8 u16 each; thread does slices tid and tid+256
    #pragma unroll
    for (int sb = 0; sb < 2; ++sb) {
        const int s    = sb * 256 + tid;
        const int ct_l = s >> 7;            // 0..3
        const int kh   = (s >> 6) & 1;
        const int lane = s & 63;
        const int gg = lane >> 4, nn = lane & 15;
        const int cl = ct_l * 16 + nn;      // local col
        const int kl = kh * 32 + gg * 8;    // local k base
        unsigned short tmp[8];
        #pragma unroll
        for (int t = 0; t < 8; ++t) tmp[t] = tw[(kl + t) * 72 + cl];
        const int fid = ks * 24 + (mat * 4 + ct_l) * 2 + kh;   // FIXED: *24
        *reinterpret_cast<u16x8*>(&WF[((size_t)fid * 64 + lane) * 8]) =
            *reinterpret_cast<const u16x8*>(tmp);
    }
}

// ---------------------------------------------------------------------------
// Kernel 1: QKV projection v5b.  M=32 tiles, grid 512 (2 blocks/CU).
// - Whole x panel (32x1024 bf16, 66KB) staged in LDS; K-loop is BARRIER-FREE.
// - W fragments read from WF as contiguous per-wave 1KB loads (no gather).
// - x half 2 (cols 512..1023) loads overlap the first 8 K-steps.
// ---------------------------------------------------------------------------
__global__ __launch_bounds__(256) void qkv_proj_kernel(
    const float* __restrict__ x, const unsigned short* __restrict__ WF,
    unsigned short* __restrict__ Qg, unsigned short* __restrict__ Kg,
    unsigned short* __restrict__ Vtg)
{
    __shared__ unsigned short xs[32 * 1040];   // [32][1040] bf16 (pad 16)
    __shared__ unsigned short vt[64 * 40];     // epilogue V transpose

    const int tid = threadIdx.x;
    const int w = tid >> 6, l = tid & 63, g = l >> 4, n = l & 15;
    const int m0 = blockIdx.x * 32;

    // ---- stage half 0 (cols 0..511): load -> convert -> LDS ----
    float4 st[16];
    #pragma unroll
    for (int j = 0; j < 16; ++j) {
        const int idx = j * 256 + tid;                // 0..4095 float4-units
        const int r = idx >> 7, c4 = (idx & 127) * 4; // 128 float4 per half-row
        st[j] = *reinterpret_cast<const float4*>(&x[(size_t)(m0 + r) * D_DIM + c4]);
    }
    #pragma unroll
    for (int j = 0; j < 16; ++j) {
        const int idx = j * 256 + tid;
        const int r = idx >> 7, c4 = (idx & 127) * 4;
        u16x4 v = { f2bf(st[j].x), f2bf(st[j].y), f2bf(st[j].z), f2bf(st[j].w) };
        *reinterpret_cast<u16x4*>(&xs[r * 1040 + c4]) = v;
    }
    __syncthreads();

    // W fragment base for this wave; frag(ct,kh,ks) is ONE contiguous load
    const unsigned short* wfb = WF + ((size_t)(w * 3) * 2 * 64 + l) * 8;
#define WFRAG(ks, ct, kh) \
    (*reinterpret_cast<const u16x8*>(wfb + (((ks) * 24 + (ct) * 2 + (kh)) * 64) * 8))

    // prefetch W frags for ks=0 (issue FIRST, then x half-1 loads behind them)
    u16x8 cw00 = WFRAG(0, 0, 0), cw10 = WFRAG(0, 1, 0), cw20 = WFRAG(0, 2, 0);
    u16x8 cw01 = WFRAG(0, 0, 1), cw11 = WFRAG(0, 1, 1), cw21 = WFRAG(0, 2, 1);

    // issue half-1 x loads (cols 512..1023) — land during ks 0..7
    #pragma unroll
    for (int j = 0; j < 16; ++j) {
        const int idx = j * 256 + tid;
        const int r = idx >> 7, c4 = (idx & 127) * 4 + 512;
        st[j] = *reinterpret_cast<const float4*>(&x[(size_t)(m0 + r) * D_DIM + c4]);
    }

    f32x4 acc[2][3];
    #pragma unroll
    for (int rb = 0; rb < 2; ++rb)
        #pragma unroll
        for (int ct = 0; ct < 3; ++ct) acc[rb][ct] = f32x4{0.f, 0.f, 0.f, 0.f};

#define KSTEP(ks, PF)  {                                                       \
    const u16x8 u00 = cw00, u10 = cw10, u20 = cw20;                            \
    const u16x8 u01 = cw01, u11 = cw11, u21 = cw21;                            \
    if (PF) {                                                                  \
        cw00 = WFRAG((ks) + 1, 0, 0); cw10 = WFRAG((ks) + 1, 1, 0);            \
        cw20 = WFRAG((ks) + 1, 2, 0); cw01 = WFRAG((ks) + 1, 0, 1);            \
        cw11 = WFRAG((ks) + 1, 1, 1); cw21 = WFRAG((ks) + 1, 2, 1);            \
    }                                                                          \
    const u16x8 a00 = *reinterpret_cast<const u16x8*>(&xs[n * 1040 + (ks) * 64 + g * 8]);          \
    const u16x8 a10 = *reinterpret_cast<const u16x8*>(&xs[(16 + n) * 1040 + (ks) * 64 + g * 8]);   \
    const u16x8 a01 = *reinterpret_cast<const u16x8*>(&xs[n * 1040 + (ks) * 64 + 32 + g * 8]);     \
    const u16x8 a11 = *reinterpret_cast<const u16x8*>(&xs[(16 + n) * 1040 + (ks) * 64 + 32 + g * 8]); \
    acc[0][0] = mfma_bf16(a00, u00, acc[0][0]);                                \
    acc[1][0] = mfma_bf16(a10, u00, acc[1][0]);                                \
    acc[0][1] = mfma_bf16(a00, u10, acc[0][1]);                                \
    acc[1][1] = mfma_bf16(a10, u10, acc[1][1]);                                \
    acc[0][2] = mfma_bf16(a00, u20, acc[0][2]);                                \
    acc[1][2] = mfma_bf16(a10, u20, acc[1][2]);                                \
    acc[0][0] = mfma_bf16(a01, u01, acc[0][0]);                                \
    acc[1][0] = mfma_bf16(a11, u01, acc[1][0]);                                \
    acc[0][1] = mfma_bf16(a01, u11, acc[0][1]);                                \
    acc[1][1] = mfma_bf16(a11, u11, acc[1][1]);                                \
    acc[0][2] = mfma_bf16(a01, u21, acc[0][2]);                                \
    acc[1][2] = mfma_bf16(a11, u21, acc[1][2]);                                \
}

    #pragma unroll
    for (int ks = 0; ks < 8; ++ks) KSTEP(ks, true);

    // ---- write x half 1, one barrier, finish ----
    #pragma unroll
    for (int j = 0; j < 16; ++j) {
        const int idx = j * 256 + tid;
        const int r = idx >> 7, c4 = (idx & 127) * 4 + 512;
        u16x4 v = { f2bf(st[j].x), f2bf(st[j].y), f2bf(st[j].z), f2bf(st[j].w) };
        *reinterpret_cast<u16x4*>(&xs[r * 1040 + c4]) = v;
    }
    __syncthreads();

    #pragma unroll
    for (int ks = 8; ks < 16; ++ks) KSTEP(ks, (ks) < 15);

    // ---- epilogue: D layout col = lane&15, row = (lane>>4)*4 + reg ----
    const int b = m0 >> 11, t0 = m0 & (T_SEQ - 1);
    #pragma unroll
    for (int rb = 0; rb < 2; ++rb)
        #pragma unroll
        for (int ct = 0; ct < 3; ++ct) {
            const int c = w * 48 + ct * 16 + n;
            #pragma unroll
            for (int r = 0; r < 4; ++r) {
                const int rin = rb * 16 + g * 4 + r;
                const float val = acc[rb][ct][r];
                if (c < 64)
                    Qg[(size_t)(m0 + rin) * H_DIM + c] = f2bf(val * 0.125f);
                else if (c < 128)
                    Kg[(size_t)(m0 + rin) * H_DIM + (c - 64)] = f2bf(val);
                else
                    vt[(c - 128) * 40 + rin] = f2bf(val);
            }
        }
    __syncthreads();
    {   // Vt[b][h][t] coalesced: 64h x 32t, 1 u16x8/thread
        const int h = tid >> 2, c8 = (tid & 3) * 8;
        *reinterpret_cast<u16x8*>(&Vtg[((size_t)(b * 64 + h)) * T_SEQ + t0 + c8]) =
            *reinterpret_cast<const u16x8*>(&vt[h * 40 + c8]);
    }
}

// ---------------------------------------------------------------------------
// Kernel 2: causal flash attention (unchanged from round 5/6 PASS).
// ---------------------------------------------------------------------------
__global__ __launch_bounds__(256) void attn_kernel(
    const unsigned short* __restrict__ Qg, const unsigned short* __restrict__ Kg,
    const unsigned short* __restrict__ Vtg, float* __restrict__ out)
{
    __shared__ unsigned short Kl[128 * 72];   // [key][h]
    __shared__ unsigned short Vl[64 * 136];   // [h][key]
    __shared__ float Om[2][64][20];           // merge buffer
    __shared__ float mred[4][64], lred[4][64];

    const int tid = threadIdx.x;
    const int wv = tid >> 6, qg = wv >> 1, kh = wv & 1;
    const int l = tid & 63, g = l >> 4, n = l & 15;

    const int i = blockIdx.x, hi = i >> 8, rest = i & 255;
    const int b = hi * 4 + (rest >> 6), j = rest & 63;
    const int qt = hi ? (63 - j) : j;
    const int q0 = qt * 32;
    const int qrow = q0 + qg * 16 + n;
    const int qmax = q0 + qg * 16 + 15;
    const int nk = (qt >> 2) + 1;

    const unsigned short* Qb = Qg + (size_t)b * T_SEQ * H_DIM;
    const unsigned short* Kb = Kg + (size_t)b * T_SEQ * H_DIM;
    const unsigned short* Vb = Vtg + (size_t)b * H_DIM * T_SEQ;

    const u16x8 qf0 = *reinterpret_cast<const u16x8*>(&Qb[(size_t)qrow * H_DIM + g * 8]);
    const u16x8 qf1 = *reinterpret_cast<const u16x8*>(&Qb[(size_t)qrow * H_DIM + 32 + g * 8]);

    f32x4 oacc[4];
    #pragma unroll
    for (int hb = 0; hb < 4; ++hb) oacc[hb] = f32x4{0.f, 0.f, 0.f, 0.f};
    float mrun = -1e30f, lrun = 0.f;

    u16x8 kst[4], vst[4];
    #pragma unroll
    for (int ii = 0; ii < 4; ++ii) {
        const int u = tid + ii * 256;
        const int kr = u >> 3, kc = (u & 7) * 8;
        const int vh = u >> 4, vc = (u & 15) * 8;
        kst[ii] = *reinterpret_cast<const u16x8*>(&Kb[(size_t)kr * H_DIM + kc]);
        vst[ii] = *reinterpret_cast<const u16x8*>(&Vb[(size_t)vh * T_SEQ + vc]);
    }

    for (int t = 0; t < nk; ++t) {
        __syncthreads();
        #pragma unroll
        for (int ii = 0; ii < 4; ++ii) {
            const int u = tid + ii * 256;
            const int kr = u >> 3, kc = (u & 7) * 8;
            const int vh = u >> 4, vc = (u & 15) * 8;
            *reinterpret_cast<u16x8*>(&Kl[kr * 72 + kc]) = kst[ii];
            *reinterpret_cast<u16x8*>(&Vl[vh * 136 + vc]) = vst[ii];
        }
        __syncthreads();
        if (t + 1 < nk) {
            const int k0n = (t + 1) * 128;
            #pragma unroll
            for (int ii = 0; ii < 4; ++ii) {
                const int u = tid + ii * 256;
                const int kr = u >> 3, kc = (u & 7) * 8;
                const int vh = u >> 4, vc = (u & 15) * 8;
                kst[ii] = *reinterpret_cast<const u16x8*>(&Kb[(size_t)(k0n + kr) * H_DIM + kc]);
                vst[ii] = *reinterpret_cast<const u16x8*>(&Vb[(size_t)vh * T_SEQ + k0n + vc]);
            }
        }

        const int kbase = kh * 64;
        if (t * 128 + kbase <= qmax) {
            f32x4 s[4];
            #pragma unroll
            for (int kb = 0; kb < 4; ++kb) {
                const u16x8 kf0 = *reinterpret_cast<const u16x8*>(&Kl[(kbase + kb * 16 + n) * 72 + g * 8]);
                const u16x8 kf1 = *reinterpret_cast<const u16x8*>(&Kl[(kbase + kb * 16 + n) * 72 + 32 + g * 8]);
                f32x4 z = f32x4{0.f, 0.f, 0.f, 0.f};
                z = mfma_bf16(kf0, qf0, z);
                z = mfma_bf16(kf1, qf1, z);
                s[kb] = z;
            }

            float sv[16];
            float tmax = -1e30f;
            #pragma unroll
            for (int kb = 0; kb < 4; ++kb)
                #pragma unroll
                for (int r = 0; r < 4; ++r) {
                    const int kk = t * 128 + kbase + kb * 16 + g * 4 + r;
                    float v = s[kb][r];
                    v = (kk <= qrow) ? v : -1e30f;
                    sv[kb * 4 + r] = v;
                    tmax = fmaxf(tmax, v);
                }
            tmax = fmaxf(tmax, __shfl_xor(tmax, 16));
            tmax = fmaxf(tmax, __shfl_xor(tmax, 32));
            const float mnew = fmaxf(mrun, tmax);
            const float scale = __expf(mrun - mnew);
            #pragma unroll
            for (int hb = 0; hb < 4; ++hb) oacc[hb] *= scale;
            lrun = lrun * scale;
            mrun = mnew;

            unsigned short pb[16];
            float ps = 0.f;
            #pragma unroll
            for (int q = 0; q < 16; ++q) {
                const float p = (sv[q] > -1e29f) ? __expf(sv[q] - mnew) : 0.f;
                pb[q] = f2bf(p);
                ps += bf2f(pb[q]);
            }
            ps += __shfl_xor(ps, 16);
            ps += __shfl_xor(ps, 32);
            lrun += ps;

            u16x8 pa0, pa1;
            #pragma unroll
            for (int q = 0; q < 8; ++q) { pa0[q] = pb[q]; pa1[q] = pb[8 + q]; }

            #pragma unroll
            for (int hb = 0; hb < 4; ++hb) {
                const unsigned short* vp = &Vl[(hb * 16 + n) * 136 + kbase + 4 * g];
                const u16x4 a0 = *reinterpret_cast<const u16x4*>(vp);
                const u16x4 a1 = *reinterpret_cast<const u16x4*>(vp + 16);
                const u16x4 b0 = *reinterpret_cast<const u16x4*>(vp + 32);
                const u16x4 b1 = *reinterpret_cast<const u16x4*>(vp + 48);
                const u16x8 vf0 = { a0[0], a0[1], a0[2], a0[3], a1[0], a1[1], a1[2], a1[3] };
                const u16x8 vf1 = { b0[0], b0[1], b0[2], b0[3], b1[0], b1[1], b1[2], b1[3] };
                oacc[hb] = mfma_bf16(vf0, pa0, oacc[hb]);
                oacc[hb] = mfma_bf16(vf1, pa1, oacc[hb]);
            }
        }
    }

    // cross-wave (kh pair) merge
    mred[wv][l] = mrun;
    lred[wv][l] = lrun;
    __syncthreads();
    const float m0v = mred[qg * 2][l],     l0v = lred[qg * 2][l];
    const float m1v = mred[qg * 2 + 1][l], l1v = lred[qg * 2 + 1][l];
    const float M = fmaxf(m0v, m1v);
    const float alpha = __expf(mrun - M);
    const float Lsum = l0v * __expf(m0v - M) + l1v * __expf(m1v - M);
    #pragma unroll
    for (int hb = 0; hb < 4; ++hb) oacc[hb] *= alpha;

    if (kh == 1) {
        #pragma unroll
        for (int hb = 0; hb < 4; ++hb)
            *reinterpret_cast<f32x4*>(&Om[qg][l][hb * 4]) = oacc[hb];
    }
    __syncthreads();
    if (kh == 0) {
        const float inv = 1.0f / Lsum;
        #pragma unroll
        for (int hb = 0; hb < 4; ++hb) {
            const f32x4 o2 = *reinterpret_cast<const f32x4*>(&Om[qg][l][hb * 4]);
            float4 o;
            o.x = (oacc[hb][0] + o2[0]) * inv;
            o.y = (oacc[hb][1] + o2[1]) * inv;
            o.z = (oacc[hb][2] + o2[2]) * inv;
            o.w = (oacc[hb][3] + o2[3]) * inv;
            *reinterpret_cast<float4*>(
                &out[((size_t)b * T_SEQ + qrow) * H_DIM + hb * 16 + 4 * g]) = o;
        }
    }
}

// ---------------------------------------------------------------------------
extern "C" void kernel_launch(void* const* d_in, const int* in_sizes, int n_in,
                              void* d_out, int out_size, void* d_ws, size_t ws_size,
                              hipStream_t stream) {
    const float* x  = (const float*)d_in[0];
    const float* Wq = (const float*)d_in[1];
    const float* Wk = (const float*)d_in[2];
    const float* Wv = (const float*)d_in[3];

    unsigned short* Qg  = (unsigned short*)d_ws;
    unsigned short* Kg  = Qg + (size_t)M_TOT * H_DIM;
    unsigned short* Vtg = Kg + (size_t)M_TOT * H_DIM;
    unsigned short* WF  = Vtg + (size_t)M_TOT * H_DIM;   // 16*24*64*8 u16 = 384KB
    float* o = (float*)d_out;

    wtrans_kernel<<<48, 256, 0, stream>>>(Wq, Wk, Wv, WF);
    qkv_proj_kernel<<<M_TOT / 32, 256, 0, stream>>>(x, WF, Qg, Kg, Vtg);
    attn_kernel<<<512, 256, 0, stream>>>(Qg, Kg, Vtg, o);
}

// Round 10
// 57.299 us; speedup vs baseline: 1.4691x; 1.0134x over previous
//
#include <hip/hip_runtime.h>

#define D_DIM 1024
#define H_DIM 64
#define T_SEQ 2048
#define B_SZ  8
#define M_TOT (B_SZ * T_SEQ)

typedef __attribute__((ext_vector_type(4))) float f32x4;
typedef __attribute__((ext_vector_type(8))) short s16x8;
typedef __attribute__((ext_vector_type(8))) unsigned short u16x8;
typedef __attribute__((ext_vector_type(4))) unsigned short u16x4;

__device__ __forceinline__ unsigned short f2bf(float x) {
    union { float f; unsigned u; } v; v.f = x;
    unsigned r = (v.u + 0x7FFFu + ((v.u >> 16) & 1u)) >> 16;   // RNE
    return (unsigned short)r;
}
__device__ __forceinline__ float bf2f(unsigned short u) {
    union { unsigned u; float f; } v; v.u = ((unsigned)u) << 16; return v.f;
}

__device__ __forceinline__ f32x4 mfma_bf16(u16x8 a, u16x8 b, f32x4 c) {
    return __builtin_amdgcn_mfma_f32_16x16x32_bf16(
        __builtin_bit_cast(s16x8, a), __builtin_bit_cast(s16x8, b), c, 0, 0, 0);
}

// async global->LDS, 16B per lane: LDS dest = wave-uniform base + lane*16
__device__ __forceinline__ void gload_lds16(const unsigned short* g, unsigned short* l) {
    __builtin_amdgcn_global_load_lds(
        (const __attribute__((address_space(1))) void*)g,
        (__attribute__((address_space(3))) void*)l, 16, 0, 0);
}

// ---------------------------------------------------------------------------
// Kernel 0: W fp32 [1024][64] (x3) -> WF bf16 in MFMA B-fragment order.
// WF[fid][lane][slot8]: fid = ks*24 + colTile*2 + kh   (colTile 0..11)
// lane = (g<<4)|n holds W[k = ks*64+kh*32+g*8+slot][colTile*16+n].
// Each fragment is a contiguous 1KB wave-chunk.
// ---------------------------------------------------------------------------
__global__ __launch_bounds__(256) void wtrans_kernel(
    const float* __restrict__ Wq, const float* __restrict__ Wk,
    const float* __restrict__ Wv, unsigned short* __restrict__ WF)
{
    __shared__ unsigned short tw[64 * 72];
    const int mat = blockIdx.x / 16;
    const int k0  = (blockIdx.x % 16) * 64;
    const int ks  = k0 >> 6;
    const float* W = (mat == 0) ? Wq : (mat == 1) ? Wk : Wv;
    const int tid = threadIdx.x;

    {
        const int r = tid >> 2, c0 = (tid & 3) * 16;
        #pragma unroll
        for (int jj = 0; jj < 4; ++jj) {
            float4 v = *reinterpret_cast<const float4*>(&W[(size_t)(k0 + r) * H_DIM + c0 + jj * 4]);
            u16x4 u = { f2bf(v.x), f2bf(v.y), f2bf(v.z), f2bf(v.w) };
            *reinterpret_cast<u16x4*>(&tw[r * 72 + c0 + jj * 4]) = u;
        }
    }
    __syncthreads();
    #pragma unroll
    for (int sb = 0; sb < 2; ++sb) {
        const int s    = sb * 256 + tid;
        const int ct_l = s >> 7;
        const int kh   = (s >> 6) & 1;
        const int lane = s & 63;
        const int gg = lane >> 4, nn = lane & 15;
        const int cl = ct_l * 16 + nn;
        const int kl = kh * 32 + gg * 8;
        unsigned short tmp[8];
        #pragma unroll
        for (int t = 0; t < 8; ++t) tmp[t] = tw[(kl + t) * 72 + cl];
        const int fid = ks * 24 + (mat * 4 + ct_l) * 2 + kh;
        *reinterpret_cast<u16x8*>(&WF[((size_t)fid * 64 + lane) * 8]) =
            *reinterpret_cast<const u16x8*>(tmp);
    }
}

// ---------------------------------------------------------------------------
// Kernel 1: QKV projection v7 (m97-style).  M=64, grid 256 (1 block/CU),
// 512 threads = 8 waves (2 row-halves x 4 col-quarters), BK=64.
// W staged via global_load_lds (1KB frags, no VGPR round-trip), single-buffer
// LDS + reg-prefetch of fragments, 2 barriers/iter, x reg-prefetch 2 deep.
// ---------------------------------------------------------------------------
__global__ __launch_bounds__(512) void qkv_proj_kernel(
    const float* __restrict__ x, const unsigned short* __restrict__ WF,
    unsigned short* __restrict__ Qg, unsigned short* __restrict__ Kg,
    unsigned short* __restrict__ Vtg)
{
    __shared__ unsigned short xb[64 * 72];     // current 64x64 x tile (bf16)
    __shared__ unsigned short wb[24 * 512];    // 24 W fragments x 1KB

    const int tid = threadIdx.x;
    const int w = tid >> 6, l = tid & 63, g = l >> 4, n = l & 15;
    const int wm = w & 1, wn = w >> 1;          // row half / col quarter
    const int m0 = blockIdx.x * 64;

    const int xr_row = tid >> 3, xr_c = (tid & 7) * 8;
    const float* xrow = &x[(size_t)(m0 + xr_row) * D_DIM + xr_c];

    f32x4 acc[2][3];
    #pragma unroll
    for (int rb = 0; rb < 2; ++rb)
        #pragma unroll
        for (int ct = 0; ct < 3; ++ct) acc[rb][ct] = f32x4{0.f, 0.f, 0.f, 0.f};

    float4 xp[2][2];   // x prefetch regs; step s lands in xp[s&1]

    // ---- prologue: stage ks=0 directly; xp[1] <- ks=1; gl_lds W(0) ----
    {
        const float4 a0 = *reinterpret_cast<const float4*>(xrow);
        const float4 a1 = *reinterpret_cast<const float4*>(xrow + 4);
        u16x8 v = { f2bf(a0.x), f2bf(a0.y), f2bf(a0.z), f2bf(a0.w),
                    f2bf(a1.x), f2bf(a1.y), f2bf(a1.z), f2bf(a1.w) };
        *reinterpret_cast<u16x8*>(&xb[xr_row * 72 + xr_c]) = v;
    }
    xp[1][0] = *reinterpret_cast<const float4*>(xrow + 64);
    xp[1][1] = *reinterpret_cast<const float4*>(xrow + 68);
    #pragma unroll
    for (int j = 0; j < 3; ++j) {
        const int slot = w * 3 + j;
        gload_lds16(WF + ((size_t)slot * 64 + l) * 8, &wb[slot * 512]);
    }

#define KITER(ks) {                                                            \
    __syncthreads();  /* B1: staging for ks complete (vmcnt+lgkm drained) */   \
    u16x8 af[2][2], wf[3][2];                                                  \
    _Pragma("unroll")                                                          \
    for (int rb = 0; rb < 2; ++rb)                                             \
        _Pragma("unroll")                                                      \
        for (int kh = 0; kh < 2; ++kh)                                         \
            af[rb][kh] = *reinterpret_cast<const u16x8*>(                      \
                &xb[(wm * 32 + rb * 16 + n) * 72 + kh * 32 + g * 8]);          \
    _Pragma("unroll")                                                          \
    for (int ct = 0; ct < 3; ++ct)                                             \
        _Pragma("unroll")                                                      \
        for (int kh = 0; kh < 2; ++kh)                                         \
            wf[ct][kh] = *reinterpret_cast<const u16x8*>(                      \
                &wb[((wn * 3 + ct) * 2 + kh) * 512 + l * 8]);                  \
    __syncthreads();  /* B2: all reads in regs -> safe to overwrite */         \
    if ((ks) < 15) {                                                           \
        _Pragma("unroll")                                                      \
        for (int j = 0; j < 3; ++j) {                                          \
            const int slot = w * 3 + j;                                        \
            gload_lds16(WF + (((size_t)((ks) + 1) * 24 + slot) * 64 + l) * 8,  \
                        &wb[slot * 512]);                                      \
        }                                                                      \
        const float4 a0 = xp[((ks) + 1) & 1][0];                               \
        const float4 a1 = xp[((ks) + 1) & 1][1];                               \
        u16x8 v = { f2bf(a0.x), f2bf(a0.y), f2bf(a0.z), f2bf(a0.w),            \
                    f2bf(a1.x), f2bf(a1.y), f2bf(a1.z), f2bf(a1.w) };          \
        *reinterpret_cast<u16x8*>(&xb[xr_row * 72 + xr_c]) = v;                \
    }                                                                          \
    if ((ks) + 2 <= 15) {                                                      \
        xp[(ks) & 1][0] = *reinterpret_cast<const float4*>(xrow + ((ks) + 2) * 64);     \
        xp[(ks) & 1][1] = *reinterpret_cast<const float4*>(xrow + ((ks) + 2) * 64 + 4); \
    }                                                                          \
    _Pragma("unroll")                                                          \
    for (int rb = 0; rb < 2; ++rb)                                             \
        _Pragma("unroll")                                                      \
        for (int ct = 0; ct < 3; ++ct) {                                       \
            acc[rb][ct] = mfma_bf16(af[rb][0], wf[ct][0], acc[rb][ct]);        \
            acc[rb][ct] = mfma_bf16(af[rb][1], wf[ct][1], acc[rb][ct]);        \
        }                                                                      \
}

    KITER(0)  KITER(1)  KITER(2)  KITER(3)
    KITER(4)  KITER(5)  KITER(6)  KITER(7)
    KITER(8)  KITER(9)  KITER(10) KITER(11)
    KITER(12) KITER(13) KITER(14) KITER(15)
#undef KITER

    // ---- epilogue: D layout col = lane&15, row = (lane>>4)*4 + reg ----
    // vt reuses xb (64x72 u16): last xb reads completed before iter-15 B2.
    const int b = m0 >> 11, t0 = m0 & (T_SEQ - 1);
    #pragma unroll
    for (int rb = 0; rb < 2; ++rb)
        #pragma unroll
        for (int ct = 0; ct < 3; ++ct) {
            const int c = wn * 48 + ct * 16 + n;
            #pragma unroll
            for (int r = 0; r < 4; ++r) {
                const int rin = wm * 32 + rb * 16 + g * 4 + r;
                const float val = acc[rb][ct][r];
                if (c < 64)
                    Qg[(size_t)(m0 + rin) * H_DIM + c] = f2bf(val * 0.125f);
                else if (c < 128)
                    Kg[(size_t)(m0 + rin) * H_DIM + (c - 64)] = f2bf(val);
                else
                    xb[(c - 128) * 72 + rin] = f2bf(val);   // vt[h][t_local]
            }
        }
    __syncthreads();
    {   // Vt[b][h][t] coalesced: 64h x 64t, one u16x8 per thread
        const int h = tid >> 3, tc = (tid & 7) * 8;
        *reinterpret_cast<u16x8*>(&Vtg[((size_t)(b * 64 + h)) * T_SEQ + t0 + tc]) =
            *reinterpret_cast<const u16x8*>(&xb[h * 72 + tc]);
    }
}

// ---------------------------------------------------------------------------
// Kernel 2: causal flash attention (unchanged from round 5/6/9 PASS).
// ---------------------------------------------------------------------------
__global__ __launch_bounds__(256) void attn_kernel(
    const unsigned short* __restrict__ Qg, const unsigned short* __restrict__ Kg,
    const unsigned short* __restrict__ Vtg, float* __restrict__ out)
{
    __shared__ unsigned short Kl[128 * 72];   // [key][h]
    __shared__ unsigned short Vl[64 * 136];   // [h][key]
    __shared__ float Om[2][64][20];           // merge buffer
    __shared__ float mred[4][64], lred[4][64];

    const int tid = threadIdx.x;
    const int wv = tid >> 6, qg = wv >> 1, kh = wv & 1;
    const int l = tid & 63, g = l >> 4, n = l & 15;

    const int i = blockIdx.x, hi = i >> 8, rest = i & 255;
    const int b = hi * 4 + (rest >> 6), j = rest & 63;
    const int qt = hi ? (63 - j) : j;
    const int q0 = qt * 32;
    const int qrow = q0 + qg * 16 + n;
    const int qmax = q0 + qg * 16 + 15;
    const int nk = (qt >> 2) + 1;

    const unsigned short* Qb = Qg + (size_t)b * T_SEQ * H_DIM;
    const unsigned short* Kb = Kg + (size_t)b * T_SEQ * H_DIM;
    const unsigned short* Vb = Vtg + (size_t)b * H_DIM * T_SEQ;

    const u16x8 qf0 = *reinterpret_cast<const u16x8*>(&Qb[(size_t)qrow * H_DIM + g * 8]);
    const u16x8 qf1 = *reinterpret_cast<const u16x8*>(&Qb[(size_t)qrow * H_DIM + 32 + g * 8]);

    f32x4 oacc[4];
    #pragma unroll
    for (int hb = 0; hb < 4; ++hb) oacc[hb] = f32x4{0.f, 0.f, 0.f, 0.f};
    float mrun = -1e30f, lrun = 0.f;

    u16x8 kst[4], vst[4];
    #pragma unroll
    for (int ii = 0; ii < 4; ++ii) {
        const int u = tid + ii * 256;
        const int kr = u >> 3, kc = (u & 7) * 8;
        const int vh = u >> 4, vc = (u & 15) * 8;
        kst[ii] = *reinterpret_cast<const u16x8*>(&Kb[(size_t)kr * H_DIM + kc]);
        vst[ii] = *reinterpret_cast<const u16x8*>(&Vb[(size_t)vh * T_SEQ + vc]);
    }

    for (int t = 0; t < nk; ++t) {
        __syncthreads();
        #pragma unroll
        for (int ii = 0; ii < 4; ++ii) {
            const int u = tid + ii * 256;
            const int kr = u >> 3, kc = (u & 7) * 8;
            const int vh = u >> 4, vc = (u & 15) * 8;
            *reinterpret_cast<u16x8*>(&Kl[kr * 72 + kc]) = kst[ii];
            *reinterpret_cast<u16x8*>(&Vl[vh * 136 + vc]) = vst[ii];
        }
        __syncthreads();
        if (t + 1 < nk) {
            const int k0n = (t + 1) * 128;
            #pragma unroll
            for (int ii = 0; ii < 4; ++ii) {
                const int u = tid + ii * 256;
                const int kr = u >> 3, kc = (u & 7) * 8;
                const int vh = u >> 4, vc = (u & 15) * 8;
                kst[ii] = *reinterpret_cast<const u16x8*>(&Kb[(size_t)(k0n + kr) * H_DIM + kc]);
                vst[ii] = *reinterpret_cast<const u16x8*>(&Vb[(size_t)vh * T_SEQ + k0n + vc]);
            }
        }

        const int kbase = kh * 64;
        if (t * 128 + kbase <= qmax) {
            f32x4 s[4];
            #pragma unroll
            for (int kb = 0; kb < 4; ++kb) {
                const u16x8 kf0 = *reinterpret_cast<const u16x8*>(&Kl[(kbase + kb * 16 + n) * 72 + g * 8]);
                const u16x8 kf1 = *reinterpret_cast<const u16x8*>(&Kl[(kbase + kb * 16 + n) * 72 + 32 + g * 8]);
                f32x4 z = f32x4{0.f, 0.f, 0.f, 0.f};
                z = mfma_bf16(kf0, qf0, z);
                z = mfma_bf16(kf1, qf1, z);
                s[kb] = z;
            }

            float sv[16];
            float tmax = -1e30f;
            #pragma unroll
            for (int kb = 0; kb < 4; ++kb)
                #pragma unroll
                for (int r = 0; r < 4; ++r) {
                    const int kk = t * 128 + kbase + kb * 16 + g * 4 + r;
                    float v = s[kb][r];
                    v = (kk <= qrow) ? v : -1e30f;
                    sv[kb * 4 + r] = v;
                    tmax = fmaxf(tmax, v);
                }
            tmax = fmaxf(tmax, __shfl_xor(tmax, 16));
            tmax = fmaxf(tmax, __shfl_xor(tmax, 32));
            const float mnew = fmaxf(mrun, tmax);
            const float scale = __expf(mrun - mnew);
            #pragma unroll
            for (int hb = 0; hb < 4; ++hb) oacc[hb] *= scale;
            lrun = lrun * scale;
            mrun = mnew;

            unsigned short pb[16];
            float ps = 0.f;
            #pragma unroll
            for (int q = 0; q < 16; ++q) {
                const float p = (sv[q] > -1e29f) ? __expf(sv[q] - mnew) : 0.f;
                pb[q] = f2bf(p);
                ps += bf2f(pb[q]);
            }
            ps += __shfl_xor(ps, 16);
            ps += __shfl_xor(ps, 32);
            lrun += ps;

            u16x8 pa0, pa1;
            #pragma unroll
            for (int q = 0; q < 8; ++q) { pa0[q] = pb[q]; pa1[q] = pb[8 + q]; }

            #pragma unroll
            for (int hb = 0; hb < 4; ++hb) {
                const unsigned short* vp = &Vl[(hb * 16 + n) * 136 + kbase + 4 * g];
                const u16x4 a0 = *reinterpret_cast<const u16x4*>(vp);
                const u16x4 a1 = *reinterpret_cast<const u16x4*>(vp + 16);
                const u16x4 b0 = *reinterpret_cast<const u16x4*>(vp + 32);
                const u16x4 b1 = *reinterpret_cast<const u16x4*>(vp + 48);
                const u16x8 vf0 = { a0[0], a0[1], a0[2], a0[3], a1[0], a1[1], a1[2], a1[3] };
                const u16x8 vf1 = { b0[0], b0[1], b0[2], b0[3], b1[0], b1[1], b1[2], b1[3] };
                oacc[hb] = mfma_bf16(vf0, pa0, oacc[hb]);
                oacc[hb] = mfma_bf16(vf1, pa1, oacc[hb]);
            }
        }
    }

    // cross-wave (kh pair) merge
    mred[wv][l] = mrun;
    lred[wv][l] = lrun;
    __syncthreads();
    const float m0v = mred[qg * 2][l],     l0v = lred[qg * 2][l];
    const float m1v = mred[qg * 2 + 1][l], l1v = lred[qg * 2 + 1][l];
    const float M = fmaxf(m0v, m1v);
    const float alpha = __expf(mrun - M);
    const float Lsum = l0v * __expf(m0v - M) + l1v * __expf(m1v - M);
    #pragma unroll
    for (int hb = 0; hb < 4; ++hb) oacc[hb] *= alpha;

    if (kh == 1) {
        #pragma unroll
        for (int hb = 0; hb < 4; ++hb)
            *reinterpret_cast<f32x4*>(&Om[qg][l][hb * 4]) = oacc[hb];
    }
    __syncthreads();
    if (kh == 0) {
        const float inv = 1.0f / Lsum;
        #pragma unroll
        for (int hb = 0; hb < 4; ++hb) {
            const f32x4 o2 = *reinterpret_cast<const f32x4*>(&Om[qg][l][hb * 4]);
            float4 o;
            o.x = (oacc[hb][0] + o2[0]) * inv;
            o.y = (oacc[hb][1] + o2[1]) * inv;
            o.z = (oacc[hb][2] + o2[2]) * inv;
            o.w = (oacc[hb][3] + o2[3]) * inv;
            *reinterpret_cast<float4*>(
                &out[((size_t)b * T_SEQ + qrow) * H_DIM + hb * 16 + 4 * g]) = o;
        }
    }
}

// ---------------------------------------------------------------------------
extern "C" void kernel_launch(void* const* d_in, const int* in_sizes, int n_in,
                              void* d_out, int out_size, void* d_ws, size_t ws_size,
                              hipStream_t stream) {
    const float* x  = (const float*)d_in[0];
    const float* Wq = (const float*)d_in[1];
    const float* Wk = (const float*)d_in[2];
    const float* Wv = (const float*)d_in[3];

    unsigned short* Qg  = (unsigned short*)d_ws;
    unsigned short* Kg  = Qg + (size_t)M_TOT * H_DIM;
    unsigned short* Vtg = Kg + (size_t)M_TOT * H_DIM;
    unsigned short* WF  = Vtg + (size_t)M_TOT * H_DIM;   // 16*24*64*8 u16 = 384KB
    float* o = (float*)d_out;

    wtrans_kernel<<<48, 256, 0, stream>>>(Wq, Wk, Wv, WF);
    qkv_proj_kernel<<<M_TOT / 64, 512, 0, stream>>>(x, WF, Qg, Kg, Vtg);
    attn_kernel<<<512, 256, 0, stream>>>(Qg, Kg, Vtg, o);
}